// Round 1
// baseline (656.296 us; speedup 1.0000x reference)
//
#include <hip/hip_runtime.h>

#define B_  16
#define IC  128
#define OC  256
#define ZD  256
#define HH  64
#define WW  64
#define FAN 1152      // IC*3*3
#define NO  294912    // OC*FAN

typedef float  fvec4 __attribute__((ext_vector_type(4)));
typedef _Float16 f16x8 __attribute__((ext_vector_type(8)));

// ---------------------------------------------------------------------------
// Kernel A: delta[b][o] = sum_z z[b][z] * head_w[o][z]
// HBM-bound on head_w (302 MB). 2 o's per thread, z in LDS (broadcast).
// ---------------------------------------------------------------------------
__global__ __launch_bounds__(256) void delta_gemm_kernel(
    const float* __restrict__ z, const float* __restrict__ head_w,
    float* __restrict__ delta) {
  __shared__ float zs[B_ * ZD];
  int tid = threadIdx.x;
  const fvec4* z4 = (const fvec4*)z;
  fvec4* zs4 = (fvec4*)zs;
  for (int i = tid; i < B_ * ZD / 4; i += 256) zs4[i] = z4[i];
  __syncthreads();

  int o_a = blockIdx.x * 512 + tid;
  int o_b = o_a + 256;
  const fvec4* hw4 = (const fvec4*)head_w;
  float acc_a[B_], acc_b[B_];
#pragma unroll
  for (int b = 0; b < B_; ++b) { acc_a[b] = 0.f; acc_b[b] = 0.f; }

  for (int zi = 0; zi < ZD / 4; ++zi) {
    fvec4 ha = hw4[(size_t)o_a * (ZD / 4) + zi];
    fvec4 hb = hw4[(size_t)o_b * (ZD / 4) + zi];
#pragma unroll
    for (int b = 0; b < B_; ++b) {
      fvec4 zv = zs4[b * (ZD / 4) + zi];
      acc_a[b] += zv.x * ha.x + zv.y * ha.y + zv.z * ha.z + zv.w * ha.w;
      acc_b[b] += zv.x * hb.x + zv.y * hb.y + zv.z * hb.z + zv.w * hb.w;
    }
  }
#pragma unroll
  for (int b = 0; b < B_; ++b) {
    delta[(size_t)b * NO + o_a] = acc_a[b];
    delta[(size_t)b * NO + o_b] = acc_b[b];
  }
}

// ---------------------------------------------------------------------------
// Kernel B: per (b, oc): standardize delta over fan_in=1152, add base weight,
// write f16 weights in permuted layout w_h[b][oc][ (ky*3+kx)*128 + ic ].
// ---------------------------------------------------------------------------
__global__ __launch_bounds__(256) void standardize_kernel(
    const float* __restrict__ delta, const float* __restrict__ base_w,
    _Float16* __restrict__ w_h) {
  int b  = blockIdx.x >> 8;
  int oc = blockIdx.x & 255;
  int tid = threadIdx.x;
  const float* d = delta + (size_t)b * NO + oc * FAN;

  float s = 0.f, s2 = 0.f;
  for (int j = tid; j < FAN; j += 256) { float v = d[j]; s += v; s2 += v * v; }
#pragma unroll
  for (int off = 32; off > 0; off >>= 1) {
    s  += __shfl_down(s, off);
    s2 += __shfl_down(s2, off);
  }
  __shared__ float rs[4], rq[4];
  if ((tid & 63) == 0) { rs[tid >> 6] = s; rq[tid >> 6] = s2; }
  __syncthreads();
  float S  = rs[0] + rs[1] + rs[2] + rs[3];
  float S2 = rq[0] + rq[1] + rq[2] + rq[3];
  const float inv_fan = 1.0f / (float)FAN;
  float mu  = S * inv_fan;
  float var = S2 * inv_fan - mu * mu;
  const float inv_sqrt2 = 0.70710678118654752f;
  float sc = rsqrtf(var + 1e-5f) * sqrtf(2.0f / (float)FAN) * inv_sqrt2;

  const float* bw = base_w + oc * FAN;
  _Float16* wp = w_h + ((size_t)b * OC + oc) * FAN;
  for (int i = tid; i < FAN; i += 256) {      // i = kk*128 + ic (write order)
    int ic = i & 127, kk = i >> 7;
    int j = ic * 9 + kk;                      // read order
    float val = bw[j] * inv_sqrt2 + (d[j] - mu) * sc;
    wp[i] = (_Float16)val;
  }
}

// ---------------------------------------------------------------------------
// Kernel C: conv as implicit GEMM, f16 MFMA 16x16x32.
// Per block: 128 oc x 128 px (2 rows of 64), K = 9*(4 chunks of 32 ic).
// grid = (32 px-tiles, 2 oc-tiles, 16 batch)
// ---------------------------------------------------------------------------
__global__ __launch_bounds__(256) void conv_mfma_kernel(
    const float* __restrict__ x, const _Float16* __restrict__ w_h,
    float* __restrict__ out) {
  __shared__ _Float16 As[128 * 32];   // [oc_local][k_local], 64B rows
  __shared__ _Float16 Bs[128 * 32];   // [px_local][k_local], 64B rows

  int tid  = threadIdx.x;
  int b    = blockIdx.z;
  int oc0  = blockIdx.y * 128;
  int y0   = blockIdx.x * 2;

  int lane = tid & 63;
  int wave = tid >> 6;
  int wm = wave >> 1, wn = wave & 1;
  int quad = lane >> 4, l16 = lane & 15;

  fvec4 acc[4][4];
#pragma unroll
  for (int i = 0; i < 4; ++i)
#pragma unroll
    for (int j = 0; j < 4; ++j) acc[i][j] = (fvec4){0.f, 0.f, 0.f, 0.f};

  // staging assignment: thread -> (row = tid>>1, 16 k at k0 = (tid&1)*16)
  int row = tid >> 1;
  int k0  = (tid & 1) * 16;
  const _Float16* wrow = w_h + ((size_t)(b * OC + oc0 + row)) * FAN + k0;
  int ry = row >> 6, xx = row & 63;   // row doubles as pixel index n

  for (int kk = 0; kk < 9; ++kk) {
    int dy = kk / 3 - 1, dx = kk % 3 - 1;
    int yy = y0 + ry + dy;
    int xs = xx + dx;
    bool valid = (yy >= 0) && (yy < HH) && (xs >= 0) && (xs < WW);
    const float* xbase = x + (((size_t)(b * IC + k0) * HH + yy) * WW + xs);

    for (int icc = 0; icc < 4; ++icc) {
      // --- stage A tile: 128 x 32 f16 (8 KB), fully coalesced 16B loads
      const fvec4* asrc = (const fvec4*)(wrow + kk * 128 + icc * 32);
      fvec4* adst = (fvec4*)(As + row * 32 + k0);
      adst[0] = asrc[0];
      adst[1] = asrc[1];

      // --- stage B tile (implicit im2col): 128 px x 32 ic f16 (8 KB)
      union { _Float16 h[16]; fvec4 f[2]; } u;
      if (valid) {
        const float* xsrc = xbase + (size_t)icc * 32 * HH * WW;
#pragma unroll
        for (int j = 0; j < 16; ++j)
          u.h[j] = (_Float16)xsrc[(size_t)j * HH * WW];
      } else {
        u.f[0] = (fvec4){0.f, 0.f, 0.f, 0.f};
        u.f[1] = (fvec4){0.f, 0.f, 0.f, 0.f};
      }
      fvec4* bdst = (fvec4*)(Bs + row * 32 + k0);
      bdst[0] = u.f[0];
      bdst[1] = u.f[1];

      __syncthreads();

      // --- fragments + MFMA
      f16x8 af[4], bf[4];
#pragma unroll
      for (int i = 0; i < 4; ++i)
        af[i] = *(const f16x8*)(As + (wm * 64 + i * 16 + l16) * 32 + quad * 8);
#pragma unroll
      for (int j = 0; j < 4; ++j)
        bf[j] = *(const f16x8*)(Bs + (wn * 64 + j * 16 + l16) * 32 + quad * 8);
#pragma unroll
      for (int i = 0; i < 4; ++i)
#pragma unroll
        for (int j = 0; j < 4; ++j)
          acc[i][j] = __builtin_amdgcn_mfma_f32_16x16x32_f16(af[i], bf[j], acc[i][j], 0, 0, 0);

      __syncthreads();
    }
  }

  // --- epilogue: D row = oc (quad*4 + r), col = pixel (l16)
#pragma unroll
  for (int i = 0; i < 4; ++i)
#pragma unroll
    for (int j = 0; j < 4; ++j) {
      int m  = oc0 + wm * 64 + i * 16 + quad * 4;
      int nn = wn * 64 + j * 16 + l16;
      int oy = y0 + (nn >> 6), ox = nn & 63;
      float* op = out + (((size_t)(b * OC + m) * HH + oy) * WW + ox);
#pragma unroll
      for (int r = 0; r < 4; ++r)
        op[(size_t)r * HH * WW] = acc[i][j][r];
    }
}

// ---------------------------------------------------------------------------
extern "C" void kernel_launch(void* const* d_in, const int* in_sizes, int n_in,
                              void* d_out, int out_size, void* d_ws, size_t ws_size,
                              hipStream_t stream) {
  const float* x      = (const float*)d_in[0];  // [16,128,64,64]
  const float* z      = (const float*)d_in[1];  // [16,256]
  const float* base_w = (const float*)d_in[2];  // [256,128,3,3]
  const float* head_w = (const float*)d_in[3];  // [294912,256]
  float* out = (float*)d_out;                   // [16,256,64,64]

  // workspace: delta fp32 (18.87 MB) then w_h f16 (9.44 MB)
  float*    delta = (float*)d_ws;
  _Float16* w_h   = (_Float16*)((char*)d_ws + (size_t)B_ * NO * sizeof(float));

  delta_gemm_kernel<<<NO / 512, 256, 0, stream>>>(z, head_w, delta);
  standardize_kernel<<<B_ * OC, 256, 0, stream>>>(delta, base_w, w_h);
  conv_mfma_kernel<<<dim3(32, 2, B_), 256, 0, stream>>>(x, w_h, out);
}

// Round 2
// 514.929 us; speedup vs baseline: 1.2745x; 1.2745x over previous
//
#include <hip/hip_runtime.h>

#define B_  16
#define IC  128
#define OC  256
#define ZD  256
#define HH  64
#define WW  64
#define FAN 1152      // IC*3*3
#define NO  294912    // OC*FAN
#define HP  66        // padded H/W

typedef float    fvec4 __attribute__((ext_vector_type(4)));
typedef _Float16 f16x8 __attribute__((ext_vector_type(8)));
typedef _Float16 f16x4 __attribute__((ext_vector_type(4)));

// ---------------------------------------------------------------------------
// Kernel A: delta[b][o] = sum_z z[b][z] * head_w[o][z]  via f16 MFMA.
// M = NO rows (256/block), N = 16 batches, K = 256 in 8 chunks of 32.
// head_w staged row-major f16 (no transpose): coalesced reads, tiny LDS use.
// ---------------------------------------------------------------------------
__global__ __launch_bounds__(256) void delta_gemm_kernel(
    const float* __restrict__ z, const float* __restrict__ head_w,
    float* __restrict__ delta) {
  __shared__ _Float16 As[256 * 40];     // [row][32 k + 8 pad], stride 80 B
  __shared__ _Float16 zsh[16 * 264];    // [b][256 k + 8 pad]
  int t = threadIdx.x;
  int row0 = blockIdx.x * 256;
  int lane = t & 63, wave = t >> 6;
  int quad = lane >> 4, l16 = lane & 15;

  // stage z once: 16x256 f32 -> f16
  for (int u = t; u < 1024; u += 256) {
    int b = u >> 6, kq = u & 63;
    fvec4 v = *(const fvec4*)&z[b * 256 + kq * 4];
    f16x4 h = {(_Float16)v.x, (_Float16)v.y, (_Float16)v.z, (_Float16)v.w};
    *(f16x4*)&zsh[b * 264 + kq * 4] = h;
  }

  fvec4 acc[4];
#pragma unroll
  for (int i = 0; i < 4; ++i) acc[i] = (fvec4){0.f, 0.f, 0.f, 0.f};

  int srow_lo = t >> 3;   // + i*32
  int skq = t & 7;

  for (int zc = 0; zc < 8; ++zc) {
    __syncthreads();      // guards zsh on first iter, As reuse on later iters
#pragma unroll
    for (int i = 0; i < 8; ++i) {
      int row = i * 32 + srow_lo;
      fvec4 v = *(const fvec4*)&head_w[(size_t)(row0 + row) * 256 + zc * 32 + skq * 4];
      f16x4 h = {(_Float16)v.x, (_Float16)v.y, (_Float16)v.z, (_Float16)v.w};
      *(f16x4*)&As[row * 40 + skq * 4] = h;
    }
    __syncthreads();
    f16x8 bfz = *(const f16x8*)&zsh[l16 * 264 + zc * 32 + quad * 8];
#pragma unroll
    for (int mt = 0; mt < 4; ++mt) {
      f16x8 af = *(const f16x8*)&As[(wave * 64 + mt * 16 + l16) * 40 + quad * 8];
      acc[mt] = __builtin_amdgcn_mfma_f32_16x16x32_f16(af, bfz, acc[mt], 0, 0, 0);
    }
  }
  // D: m-row = quad*4 + r, n-col = l16 = b
#pragma unroll
  for (int mt = 0; mt < 4; ++mt) {
    int gr = row0 + wave * 64 + mt * 16 + quad * 4;
#pragma unroll
    for (int r = 0; r < 4; ++r)
      delta[(size_t)l16 * NO + gr + r] = acc[mt][r];
  }
}

// ---------------------------------------------------------------------------
// Kernel B: standardize delta over fan_in per (b,oc), add base weight,
// write f16 weights w_h[b][oc][(ky*3+kx)*128 + ic].  (round-1 validated)
// ---------------------------------------------------------------------------
__global__ __launch_bounds__(256) void standardize_kernel(
    const float* __restrict__ delta, const float* __restrict__ base_w,
    _Float16* __restrict__ w_h) {
  int b  = blockIdx.x >> 8;
  int oc = blockIdx.x & 255;
  int tid = threadIdx.x;
  const float* d = delta + (size_t)b * NO + oc * FAN;

  float s = 0.f, s2 = 0.f;
  for (int j = tid; j < FAN; j += 256) { float v = d[j]; s += v; s2 += v * v; }
#pragma unroll
  for (int off = 32; off > 0; off >>= 1) {
    s  += __shfl_down(s, off);
    s2 += __shfl_down(s2, off);
  }
  __shared__ float rs[4], rq[4];
  if ((tid & 63) == 0) { rs[tid >> 6] = s; rq[tid >> 6] = s2; }
  __syncthreads();
  float S  = rs[0] + rs[1] + rs[2] + rs[3];
  float S2 = rq[0] + rq[1] + rq[2] + rq[3];
  const float inv_fan = 1.0f / (float)FAN;
  float mu  = S * inv_fan;
  float var = S2 * inv_fan - mu * mu;
  const float inv_sqrt2 = 0.70710678118654752f;
  float sc = rsqrtf(var + 1e-5f) * sqrtf(2.0f / (float)FAN) * inv_sqrt2;

  const float* bw = base_w + oc * FAN;
  _Float16* wp = w_h + ((size_t)b * OC + oc) * FAN;
  for (int i = tid; i < FAN; i += 256) {      // i = kk*128 + ic (write order)
    int ic = i & 127, kk = i >> 7;
    int j = ic * 9 + kk;                      // read order
    float val = bw[j] * inv_sqrt2 + (d[j] - mu) * sc;
    wp[i] = (_Float16)val;
  }
}

// ---------------------------------------------------------------------------
// Kernel X: x (f32 NCHW) -> x_h (f16 NHWC, zero-padded [16][66][66][128]).
// LDS tile transpose; grid = (66 padded rows, 16 batches).
// ---------------------------------------------------------------------------
__global__ __launch_bounds__(256) void xpose_kernel(
    const float* __restrict__ x, _Float16* __restrict__ x_h) {
  int yp = blockIdx.x;
  int b  = blockIdx.y;
  int t  = threadIdx.x;
  _Float16* orow = x_h + ((size_t)(b * HP + yp)) * HP * IC;

  if (yp == 0 || yp == HP - 1) {            // full zero row (incl. corners)
    fvec4 zz = (fvec4){0.f, 0.f, 0.f, 0.f};
    for (int u = t; u < HP * IC / 8; u += 256)   // 1056 x 16B
      ((fvec4*)orow)[u] = zz;
    return;
  }
  int y = yp - 1;
  __shared__ float tile[128 * 65];          // [ic][x], stride 65 (odd: 2-way free)
#pragma unroll
  for (int i = 0; i < 8; ++i) {
    int F = i * 256 + t;
    int ic = F >> 4, xq = F & 15;
    fvec4 v = *(const fvec4*)&x[(((size_t)b * IC + ic) * HH + y) * WW + xq * 4];
    float* tp = &tile[ic * 65 + xq * 4];
    tp[0] = v.x; tp[1] = v.y; tp[2] = v.z; tp[3] = v.w;
  }
  __syncthreads();
#pragma unroll
  for (int j = 0; j < 4; ++j) {
    int u = j * 256 + t;
    int px = u >> 4, icg = u & 15;
    _Float16 h[8];
#pragma unroll
    for (int c = 0; c < 8; ++c) h[c] = (_Float16)tile[(icg * 8 + c) * 65 + px];
    *(f16x8*)&orow[(px + 1) * IC + icg * 8] = *(f16x8*)h;
  }
  if (t < 32) {                             // x' = 0 and x' = 65 pads
    int side = t >> 4, icg = t & 15;
    fvec4 zz = (fvec4){0.f, 0.f, 0.f, 0.f};
    *(fvec4*)&orow[(side ? (HP - 1) * IC : 0) + icg * 8] = zz;
  }
}

// ---------------------------------------------------------------------------
// Kernel C: conv as implicit GEMM, f16 MFMA 16x16x32, BK=64, padded-NHWC x.
// Block: 128 oc x 128 px; grid = (32 px-tiles, 2 oc-tiles, 16 b).
// LDS pads (+8 f16) give bank-uniform b128 fragment reads.
// ---------------------------------------------------------------------------
__global__ __launch_bounds__(256) void conv_mfma_kernel(
    const _Float16* __restrict__ x_h, const _Float16* __restrict__ w_h,
    float* __restrict__ out) {
  __shared__ _Float16 As[128 * 72];   // [oc][64 k + 8 pad]
  __shared__ _Float16 Bs[128 * 72];   // [px][64 k + 8 pad]
  int t = threadIdx.x;
  int b = blockIdx.z;
  int oc0 = blockIdx.y * 128;
  int y0 = blockIdx.x * 2;
  int lane = t & 63, wave = t >> 6;
  int wm = wave >> 1, wn = wave & 1;
  int quad = lane >> 4, l16 = lane & 15;

  fvec4 acc[4][4];
#pragma unroll
  for (int i = 0; i < 4; ++i)
#pragma unroll
    for (int j = 0; j < 4; ++j) acc[i][j] = (fvec4){0.f, 0.f, 0.f, 0.f};

  int srow = t >> 1;          // A row (oc) == B row (px)
  int half = t & 1;           // which 32-f16 half of the 64-k slab
  const _Float16* wbase = w_h + ((size_t)(b * OC + oc0 + srow)) * FAN + half * 32;
  int ry = srow >> 6, xx = srow & 63;

  for (int kk = 0; kk < 9; ++kk) {
    int ky = kk / 3, kx = kk % 3;
    int yp = y0 + ry + ky;     // pad offset +1 cancels with dy = ky-1
    int xp = xx + kx;
    const _Float16* xbase =
        x_h + (((size_t)(b * HP + yp)) * HP + xp) * IC + half * 32;
#pragma unroll
    for (int icc = 0; icc < 2; ++icc) {
      const fvec4* asrc = (const fvec4*)(wbase + kk * 128 + icc * 64);
      const fvec4* bsrc = (const fvec4*)(xbase + icc * 64);
      fvec4 a0 = asrc[0], a1 = asrc[1], a2 = asrc[2], a3 = asrc[3];
      fvec4 b0 = bsrc[0], b1 = bsrc[1], b2 = bsrc[2], b3 = bsrc[3];
      __syncthreads();        // protect LDS from previous iteration's readers
      fvec4* adst = (fvec4*)(As + srow * 72 + half * 32);
      adst[0] = a0; adst[1] = a1; adst[2] = a2; adst[3] = a3;
      fvec4* bdst = (fvec4*)(Bs + srow * 72 + half * 32);
      bdst[0] = b0; bdst[1] = b1; bdst[2] = b2; bdst[3] = b3;
      __syncthreads();
#pragma unroll
      for (int ks = 0; ks < 2; ++ks) {
        f16x8 af[4], bf[4];
#pragma unroll
        for (int i = 0; i < 4; ++i)
          af[i] = *(const f16x8*)&As[(wm * 64 + i * 16 + l16) * 72 + ks * 32 + quad * 8];
#pragma unroll
        for (int j = 0; j < 4; ++j)
          bf[j] = *(const f16x8*)&Bs[(wn * 64 + j * 16 + l16) * 72 + ks * 32 + quad * 8];
#pragma unroll
        for (int i = 0; i < 4; ++i)
#pragma unroll
          for (int j = 0; j < 4; ++j)
            acc[i][j] = __builtin_amdgcn_mfma_f32_16x16x32_f16(af[i], bf[j], acc[i][j], 0, 0, 0);
      }
    }
  }

  // epilogue (round-1 validated): D row = oc (quad*4 + r), col = pixel (l16)
#pragma unroll
  for (int i = 0; i < 4; ++i)
#pragma unroll
    for (int j = 0; j < 4; ++j) {
      int m  = oc0 + wm * 64 + i * 16 + quad * 4;
      int nn = wn * 64 + j * 16 + l16;
      int oy = y0 + (nn >> 6), ox = nn & 63;
      float* op = out + (((size_t)(b * OC + m) * HH + oy) * WW + ox);
#pragma unroll
      for (int r = 0; r < 4; ++r)
        op[(size_t)r * HH * WW] = acc[i][j][r];
    }
}

// ---------------------------------------------------------------------------
extern "C" void kernel_launch(void* const* d_in, const int* in_sizes, int n_in,
                              void* d_out, int out_size, void* d_ws, size_t ws_size,
                              hipStream_t stream) {
  const float* x      = (const float*)d_in[0];  // [16,128,64,64]
  const float* z      = (const float*)d_in[1];  // [16,256]
  const float* base_w = (const float*)d_in[2];  // [256,128,3,3]
  const float* head_w = (const float*)d_in[3];  // [294912,256]
  float* out = (float*)d_out;                   // [16,256,64,64]

  // ws layout (peak 28.3 MB, same as validated round 1):
  //   [0, 9.44 MB)            w_h  (f16, live to the end)
  //   [9.44 MB, 28.31 MB)     delta (f32) -> REUSED as x_h (f16) after std
  _Float16* w_h   = (_Float16*)d_ws;
  float*    delta = (float*)((char*)d_ws + (size_t)B_ * OC * FAN * sizeof(_Float16));
  _Float16* x_h   = (_Float16*)delta;           // aliased: written after std reads delta

  delta_gemm_kernel<<<NO / 256, 256, 0, stream>>>(z, head_w, delta);
  standardize_kernel<<<B_ * OC, 256, 0, stream>>>(delta, base_w, w_h);
  xpose_kernel<<<dim3(HP, B_), 256, 0, stream>>>(x, x_h);   // overwrites delta region
  conv_mfma_kernel<<<dim3(32, 2, B_), 256, 0, stream>>>(x_h, w_h, out);
}